// Round 17
// baseline (119.365 us; speedup 1.0000x reference)
//
#include <hip/hip_runtime.h>
#include <type_traits>

#define S_LEN 2048
#define NHEAD 16
#define DHEAD 64
#define EMB   1024
#define NBATCH 2

typedef __bf16 bf16_t;
typedef bf16_t bf16x8 __attribute__((ext_vector_type(8)));
typedef float  f32x4  __attribute__((ext_vector_type(4)));
typedef unsigned short us_t;
typedef us_t   us8    __attribute__((ext_vector_type(8)));
typedef us_t   us4    __attribute__((ext_vector_type(4)));
typedef unsigned int u32x4 __attribute__((ext_vector_type(4)));
typedef unsigned int u32x2 __attribute__((ext_vector_type(2)));
typedef short  s16x4  __attribute__((ext_vector_type(4)));

static __device__ __forceinline__ bf16x8 ld_bf16x8(const us_t* p) {
  return __builtin_bit_cast(bf16x8, *reinterpret_cast<const us8*>(p));
}
static __device__ __forceinline__ us_t f2bf(float f) {
  bf16_t h = (bf16_t)f;
  return __builtin_bit_cast(us_t, h);
}
// packed f32x2 -> bf16x2 (1 instr; RNE on gfx950)
static __device__ __forceinline__ unsigned cvt_pk_bf16(float lo, float hi) {
  unsigned r;
  asm("v_cvt_pk_bf16_f32 %0, %1, %2" : "=v"(r) : "v"(lo), "v"(hi));
  return r;
}
#if __has_builtin(__builtin_amdgcn_exp2f)
#define EXP2(x) __builtin_amdgcn_exp2f(x)
#else
#define EXP2(x) exp2f(x)
#endif
// async global->LDS, 16B per lane. LDS dest = wave-uniform base + lane*16.
static __device__ __forceinline__ void gload16(const void* g, void* lds) {
  __builtin_amdgcn_global_load_lds((const __attribute__((address_space(1))) void*)g,
                                   (__attribute__((address_space(3))) void*)lds,
                                   16, 0, 0);
}

// ---------------- prep: weight transpose + fp32->bf16 (4 weights, z-dim) ----
__global__ __launch_bounds__(256) void prep(const float* __restrict__ W0,
                                            const float* __restrict__ W1,
                                            const float* __restrict__ W2,
                                            const float* __restrict__ W3,
                                            us_t* __restrict__ T0,
                                            us_t* __restrict__ T1,
                                            us_t* __restrict__ T2,
                                            us_t* __restrict__ T3) {
  __shared__ float tile[32][33];
  const int z = blockIdx.z;
  const float* W = (z == 0) ? W0 : (z == 1) ? W1 : (z == 2) ? W2 : W3;
  us_t* WT = (z == 0) ? T0 : (z == 1) ? T1 : (z == 2) ? T2 : T3;
  const int n0 = blockIdx.x * 32, k0 = blockIdx.y * 32;
  const int tx = threadIdx.x & 31, ty = threadIdx.x >> 5;
#pragma unroll
  for (int i = 0; i < 32; i += 8)
    tile[ty + i][tx] = W[(size_t)(k0 + ty + i) * EMB + n0 + tx];
  __syncthreads();
#pragma unroll
  for (int i = 0; i < 32; i += 8)
    WT[(size_t)(n0 + ty + i) * EMB + k0 + tx] = f2bf(tile[tx][ty + i]);
}

// ---------------- 128x128 GEMM core (BK=32) ---------------------------------
// AF32: fp32 A reg-pipeline (depth 2) + 3-buffer B staging (depth 2): per
//       iter, a_write's implicit vmcnt(2) drains both A(ks+1) and B(ks+1);
//       B(ks+2)+A(ks+2) stay in flight across the barrier (~1.3 iter cover).
// else: bf16 A via global_load_lds, 3-buffer deep staging (R14-verified).
//   MODE 0: bf16 [(b*16+h)][s][d]; MODE 1: bf16 [(b*16+h)][d][s] (us4 store);
//   MODE 2: fp32 [m][n]
template<int MODE, bool AF32>
static __device__ __forceinline__ void gemm_core(const void* __restrict__ Ap,
                                                 const us_t* __restrict__ BT,
                                                 void* __restrict__ O,
                                                 int mt, int nt,
                                                 char (*As)[8192], char (*Bs)[8192]) {
  const int lane = threadIdx.x & 63;
  const int wave = threadIdx.x >> 6;
  const int wm = (wave >> 1) * 64;
  const int wn = (wave & 1) * 64;
  const int lr = lane & 15;
  const int lg = lane >> 4;
  constexpr int NK = EMB / 32;   // 32

  f32x4 acc[4][4] = {};

  auto stageB = [&](int buf, int k0) {
#pragma unroll
    for (int i = 0; i < 2; ++i) {
      const int seg = wave * 2 + i;
      const int r = seg * 16 + (lane >> 2);
      gload16((const char*)BT + ((size_t)(nt * 128 + r) * EMB + k0) * 2 + (lane & 3) * 16,
              &Bs[buf][seg * 1024]);
    }
  };
  auto stageA16 = [&](int buf, int k0) {
#pragma unroll
    for (int i = 0; i < 2; ++i) {
      const int seg = wave * 2 + i;
      const int r = seg * 16 + (lane >> 2);
      gload16((const char*)Ap + ((size_t)(mt * 128 + r) * EMB + k0) * 2 + (lane & 3) * 16,
              &As[buf][seg * 1024]);
    }
  };
  auto a_load = [&](f32x4 (&ar)[2][2], int k0) {
#pragma unroll
    for (int i = 0; i < 2; ++i) {
      const int seg = wave * 2 + i;
      const int r = seg * 16 + (lane >> 2);
      const float* ap = (const float*)Ap + (size_t)(mt * 128 + r) * EMB + k0 + (lane & 3) * 8;
      ar[i][0] = *reinterpret_cast<const f32x4*>(ap);
      ar[i][1] = *reinterpret_cast<const f32x4*>(ap + 4);
    }
  };
  auto a_write = [&](f32x4 (&ar)[2][2], int buf) {
#pragma unroll
    for (int i = 0; i < 2; ++i) {
      const int seg = wave * 2 + i;
      u32x4 w = { cvt_pk_bf16(ar[i][0][0], ar[i][0][1]), cvt_pk_bf16(ar[i][0][2], ar[i][0][3]),
                  cvt_pk_bf16(ar[i][1][0], ar[i][1][1]), cvt_pk_bf16(ar[i][1][2], ar[i][1][3]) };
      *reinterpret_cast<u32x4*>(&As[buf][seg * 1024 + lane * 16]) = w;
    }
  };
  auto mfma_step = [&](int ab, int bb) {
    bf16x8 af[4], bfr[4];
#pragma unroll
    for (int i = 0; i < 4; ++i)
      af[i] = ld_bf16x8((const us_t*)&As[ab][(wm + 16 * i + lr) * 64 + lg * 16]);
#pragma unroll
    for (int j = 0; j < 4; ++j)
      bfr[j] = ld_bf16x8((const us_t*)&Bs[bb][(wn + 16 * j + lr) * 64 + lg * 16]);
#pragma unroll
    for (int i = 0; i < 4; ++i)
#pragma unroll
      for (int j = 0; j < 4; ++j)
        acc[i][j] = __builtin_amdgcn_mfma_f32_16x16x32_bf16(af[i], bfr[j], acc[i][j], 0, 0, 0);
  };

  if constexpr (AF32) {
    // Depth-2 pipeline on BOTH operands. Per iter: a_write implicitly waits
    // A(ks+1) with vmcnt(2) (B(ks+2) newer) -> drains B(ks+1) (older) free;
    // B(ks+2)+A(ks+2)=6 loads fly across the barrier.
    f32x4 arE[2][2], arO[2][2];
    a_load(arE, 0);                  // A0 (4)
    stageB(0, 0);                    // B0 (2)
    stageB(1, 32);                   // B1 (2)
    a_write(arE, 0);                 // waits A0 (implicit vmcnt(4))
    a_load(arO, 32);                 // A1 (4)
    asm volatile("s_waitcnt vmcnt(6)" ::: "memory");   // drain B0; keep B1,A1
    asm volatile("s_waitcnt lgkmcnt(0)" ::: "memory");
    __builtin_amdgcn_s_barrier();

    int u = 0;                       // Bs index for even half (= ks%3)
#pragma unroll 1
    for (int ks = 0; ks < NK - 4; ks += 2) {
      const int s_e = (u + 2 > 2) ? u - 1 : u + 2;   // (ks+2)%3
      const int u_o = (u + 1 > 2) ? 0 : u + 1;       // (ks+1)%3
      // even half: consume tile ks
      stageB(s_e, (ks + 2) * 32);
      mfma_step(0, u);
      a_write(arO, 1);               // waits A(ks+1); drains B(ks+1)
      a_load(arE, (ks + 2) * 32);
      asm volatile("s_waitcnt vmcnt(6)" ::: "memory");
      asm volatile("s_waitcnt lgkmcnt(0)" ::: "memory");
      __builtin_amdgcn_s_barrier();
      // odd half: consume tile ks+1
      stageB(u, (ks + 3) * 32);      // (ks+3)%3 == u
      mfma_step(1, u_o);
      a_write(arE, 0);               // waits A(ks+2); drains B(ks+2)
      a_load(arO, (ks + 3) * 32);
      asm volatile("s_waitcnt vmcnt(6)" ::: "memory");
      asm volatile("s_waitcnt lgkmcnt(0)" ::: "memory");
      __builtin_amdgcn_s_barrier();
      u = (u + 2 > 2) ? u - 1 : u + 2;
    }
    // static tail: tiles 28..31 (u == 28%3 == 1 here)
    stageB(0, 30 * 32);              // 30%3 == 0
    mfma_step(0, 1);                 // tile 28 (28%3==1)
    a_write(arO, 1);                 // A29; drains B29
    a_load(arE, 30 * 32);
    asm volatile("s_waitcnt vmcnt(6)" ::: "memory");
    asm volatile("s_waitcnt lgkmcnt(0)" ::: "memory");
    __builtin_amdgcn_s_barrier();

    stageB(1, 31 * 32);              // 31%3 == 1
    mfma_step(1, 2);                 // tile 29 (29%3==2)
    a_write(arE, 0);                 // A30; drains B30
    a_load(arO, 31 * 32);
    asm volatile("s_waitcnt vmcnt(6)" ::: "memory");
    asm volatile("s_waitcnt lgkmcnt(0)" ::: "memory");
    __builtin_amdgcn_s_barrier();

    mfma_step(0, 0);                 // tile 30 (30%3==0)
    a_write(arO, 1);                 // A31; implicit vmcnt(0) drains B31
    asm volatile("s_waitcnt vmcnt(0)" ::: "memory");
    asm volatile("s_waitcnt lgkmcnt(0)" ::: "memory");
    __builtin_amdgcn_s_barrier();

    mfma_step(1, 1);                 // tile 31 (31%3==1)
  } else {
    // 3-buffer deep staging: stage ks+2 each iter; vmcnt(4) drains ks+1 only.
    stageA16(0, 0);  stageB(0, 0);
    stageA16(1, 32); stageB(1, 32);
    asm volatile("s_waitcnt vmcnt(4)" ::: "memory");
    __builtin_amdgcn_s_barrier();
    for (int ks = 0; ks < NK; ++ks) {
      const int cur = ks % 3;
      if (ks + 2 < NK) { stageA16((ks + 2) % 3, (ks + 2) * 32); stageB((ks + 2) % 3, (ks + 2) * 32); }
      mfma_step(cur, cur);
      if (ks + 1 < NK) {
        if (ks + 2 < NK) asm volatile("s_waitcnt vmcnt(4)" ::: "memory");
        else             asm volatile("s_waitcnt vmcnt(0)" ::: "memory");
        __builtin_amdgcn_s_barrier();
      }
    }
  }

  const int crow = (lane >> 4) * 4;
#pragma unroll
  for (int i = 0; i < 4; ++i)
#pragma unroll
    for (int j = 0; j < 4; ++j) {
      if constexpr (MODE == 1) {
        // Vt: o[(bh*64+d)*2048 + s]; consecutive r == consecutive s -> us4
        const int m = mt * 128 + wm + 16 * i + crow;     // s base (aligned 4)
        const int n = nt * 128 + wn + 16 * j + lr;       // d
        const int b = m >> 11, s = m & (S_LEN - 1);
        const int h = n >> 6, d = n & 63;
        us4 w;
#pragma unroll
        for (int r = 0; r < 4; ++r) w[r] = f2bf(acc[i][j][r]);
        *reinterpret_cast<us4*>((us_t*)O +
            ((size_t)(b * NHEAD + h) * DHEAD + d) * S_LEN + s) = w;
      } else {
#pragma unroll
        for (int r = 0; r < 4; ++r) {
          const int m = mt * 128 + wm + 16 * i + crow + r;
          const int n = nt * 128 + wn + 16 * j + lr;
          const float val = acc[i][j][r];
          if constexpr (MODE == 2) {
            ((float*)O)[(size_t)m * EMB + n] = val;
          } else {
            us_t* o = (us_t*)O;
            const int b = m >> 11, s = m & (S_LEN - 1);
            const int h = n >> 6, d = n & 63;
            o[(((size_t)(b * NHEAD + h) * S_LEN + s) << 6) + d] = f2bf(val);
          }
        }
      }
    }
}

// merged projection GEMMs (fp32 A, fused cvt, depth-2 A and B pipelines)
__global__ __launch_bounds__(256, 3) void proj3(const float* __restrict__ A0,
                                                const float* __restrict__ A1,
                                                const float* __restrict__ A2,
                                                const us_t* __restrict__ B0,
                                                const us_t* __restrict__ B1,
                                                const us_t* __restrict__ B2,
                                                us_t* __restrict__ O0,
                                                us_t* __restrict__ O1,
                                                us_t* __restrict__ O2) {
  __shared__ char As[2][8192];
  __shared__ char Bs[3][8192];
  const int f = blockIdx.x;
  const int w = (f & 7) * 96 + (f >> 3);     // XCD x owns works [96x, 96x+96)
  const int z = w >> 8;                       // /256
  const int rem = w & 255;
  const int mt = rem >> 3, nt = rem & 7;      // nt fastest: 8 blocks share A panel
  const float* A = (z == 0) ? A0 : (z == 1) ? A1 : A2;
  const us_t* BT = (z == 0) ? B0 : (z == 1) ? B1 : B2;
  us_t* O = (z == 0) ? O0 : (z == 1) ? O1 : O2;
  if (z < 2)
    gemm_core<0, true>(A, BT, O, mt, nt, As, Bs);
  else
    gemm_core<1, true>(A, BT, O, mt, nt, As, Bs);
}

// final GEMM: AO[4096,1024] @ Wo -> fp32; flat grid 256, XCD-chunked
__global__ __launch_bounds__(256) void gemmout(const us_t* __restrict__ A,
                                               const us_t* __restrict__ BT,
                                               float* __restrict__ O) {
  __shared__ char As[3][8192];
  __shared__ char Bs[3][8192];
  const int f = blockIdx.x;
  const int w = (f & 7) * 32 + (f >> 3);
  const int mt = w >> 3, nt = w & 7;
  gemm_core<2, false>(A, BT, O, mt, nt, As, Bs);
}

// ---------------- flash attention, QBLK=64, swapped-QK^T (R8-verified) ------
// Qh,Kh: bf16 [B*H][S][64]; Vt: bf16 [B*H][64][S]; AO: bf16 [B][S][H*64]
// qt snake-remap: co-resident blocks {flat,+256,+512,+768} (same bh) get
// qt sums == 62 on every CU -> balanced load, no tail idling.
__global__ __launch_bounds__(256, 4) void attn64(const us_t* __restrict__ Qh,
                                                 const us_t* __restrict__ Kh,
                                                 const us_t* __restrict__ Vt,
                                                 us_t* __restrict__ AO) {
  __shared__ char Ks[2][8192];
  __shared__ char Vs[2][8192];
  const int flat = blockIdx.y * 32 + blockIdx.x;
  const int bh = (flat & 7) * 4 + ((flat >> 3) & 3);   // same bh -> same XCD
  const int g = flat >> 5;                             // 0..31
  const int Q = g >> 3, p = g & 7;
  const int qt = (Q == 0) ? 31 - p : (Q == 1) ? 16 + p : (Q == 2) ? 15 - p : p;
  const int lane = threadIdx.x & 63;
  const int wave = threadIdx.x >> 6;
  const int lr = lane & 15;
  const int lg = lane >> 4;
  const int q_glob = qt * 64 + wave * 16 + lr;         // this lane's q row

  const us_t* qbase = Qh + ((size_t)bh * S_LEN + q_glob) * DHEAD;
  bf16x8 qf[2] = { ld_bf16x8(qbase + lg * 8), ld_bf16x8(qbase + 32 + lg * 8) };

  const us_t* kbase0 = Kh + (size_t)bh * S_LEN * DHEAD;
  const us_t* vbase0 = Vt + (size_t)bh * DHEAD * S_LEN;

  // loop-invariant swizzled LDS byte offsets (SROA'd to VGPRs)
  int koff[8];
#pragma unroll
  for (int ks = 0; ks < 2; ++ks)
#pragma unroll
    for (int j = 0; j < 4; ++j)
      koff[ks * 4 + j] = (16 * j + lr) * 128 + ((ks * 64 + lg * 16) ^ ((lr & 7) << 4));
  int voff[16];
#pragma unroll
  for (int jk = 0; jk < 4; ++jk)
#pragma unroll
    for (int jd = 0; jd < 4; ++jd)
      voff[jk * 4 + jd] = (16 * jd + lr) * 128 + ((32 * jk + 8 * lg) ^ ((lr & 7) << 4));

  auto stage = [&](int buf, int t0) {
#pragma unroll
    for (int i = 0; i < 2; ++i) {
      const int seg = wave * 2 + i;
      const int r = seg * 8 + (lane >> 3);
      const int c16 = (lane & 7) ^ (lane >> 3);
      gload16(kbase0 + (size_t)(t0 + r) * DHEAD + c16 * 8, &Ks[buf][seg * 1024]);
      gload16(vbase0 + (size_t)r * S_LEN + t0 + c16 * 8, &Vs[buf][seg * 1024]);
    }
  };

  f32x4 oaccT[4] = {};          // O^T block jd: row d=16jd+4lg+reg, col q=lr
  float mrow = -1e9f;           // running max, log2-scaled domain
  float lsum = 0.f;             // per-lane partial sum
  const float c = 0.045084220f; // (1/32) * log2(e)

  stage(0, 0);
  __syncthreads();

  for (int tt = 0; tt <= qt; ++tt) {
    const int cur = tt & 1;
    if (tt < qt) stage(cur ^ 1, (tt + 1) * 64);

    // ---- S^T = K.Q^T : sc[j] rows t=16j+4lg+r, col q=lr ----
    f32x4 sc[4] = {};
    __builtin_amdgcn_s_setprio(1);
#pragma unroll
    for (int ks = 0; ks < 2; ++ks)
#pragma unroll
      for (int j = 0; j < 4; ++j) {
        bf16x8 ak = ld_bf16x8((const us_t*)&Ks[cur][koff[ks * 4 + j]]);
        sc[j] = __builtin_amdgcn_mfma_f32_16x16x32_bf16(ak, qf[ks], sc[j], 0, 0, 0);
      }
    __builtin_amdgcn_s_setprio(0);

    // ---- mask (diagonal tile only): keep t<q, plus [0,0] ----
    if (tt == qt) {
#pragma unroll
      for (int j = 0; j < 4; ++j)
#pragma unroll
        for (int r = 0; r < 4; ++r) {
          const int t_g = tt * 64 + 16 * j + 4 * lg + r;
          if (!((t_g < q_glob) || (q_glob == 0 && t_g == 0))) sc[j][r] = -1e30f;
        }
    }

    // ---- in-lane max (balanced tree); defer-max rescale (rarely taken) ----
    float mj[4];
#pragma unroll
    for (int j = 0; j < 4; ++j)
      mj[j] = fmaxf(fmaxf(sc[j][0], sc[j][1]), fmaxf(sc[j][2], sc[j][3]));
    const float mx = fmaxf(fmaxf(mj[0], mj[1]), fmaxf(mj[2], mj[3]));
    const float mxc = mx * c;
    if (__any(mxc > mrow + 8.f)) {
      float mc = mxc;
      mc = fmaxf(mc, __shfl_xor(mc, 16, 64));
      mc = fmaxf(mc, __shfl_xor(mc, 32, 64));
      const float m2 = fmaxf(mrow, mc);
      const float alpha = EXP2(mrow - m2);
      lsum *= alpha;
#pragma unroll
      for (int j = 0; j < 4; ++j)
#pragma unroll
        for (int r = 0; r < 4; ++r) oaccT[j][r] *= alpha;
      mrow = m2;
    }

    // ---- p = exp2(s*c - m); pack bf16 pairs via v_cvt_pk_bf16_f32 ----
    unsigned int pk[4][2];
    float ps = 0.f;
#pragma unroll
    for (int j = 0; j < 4; ++j) {
      float p0 = EXP2(__builtin_fmaf(sc[j][0], c, -mrow));
      float p1 = EXP2(__builtin_fmaf(sc[j][1], c, -mrow));
      float p2 = EXP2(__builtin_fmaf(sc[j][2], c, -mrow));
      float p3 = EXP2(__builtin_fmaf(sc[j][3], c, -mrow));
      ps += (p0 + p1) + (p2 + p3);
      pk[j][0] = cvt_pk_bf16(p0, p1);
      pk[j][1] = cvt_pk_bf16(p2, p3);
    }
    lsum += ps;

    // ---- O^T += V^T.P^T via 16x16x16: P C-layout IS the B-frag layout ----
    __builtin_amdgcn_s_setprio(1);
#pragma unroll
    for (int jk = 0; jk < 4; ++jk) {
      s16x4 pf = __builtin_bit_cast(s16x4, (u32x2){pk[jk][0], pk[jk][1]});
#pragma unroll
      for (int jd = 0; jd < 4; ++jd) {
        s16x4 av = __builtin_bit_cast(s16x4,
            *reinterpret_cast<const us4*>(&Vs[cur][voff[jk * 4 + jd]]));
        oaccT[jd] = __builtin_amdgcn_mfma_f32_16x16x16bf16_1k(av, pf, oaccT[jd], 0, 0, 0);
      }
    }
    __builtin_amdgcn_s_setprio(0);
    __syncthreads();
  }

  // ---- finalize: cross-lane lsum, normalize, store O^T ----
  lsum += __shfl_xor(lsum, 16, 64);
  lsum += __shfl_xor(lsum, 32, 64);
  const float inv = 1.0f / lsum;
  const int b = bh >> 4, h = bh & 15;
  us_t* aout = AO + (size_t)(b * S_LEN + q_glob) * EMB + h * DHEAD;
#pragma unroll
  for (int j = 0; j < 4; ++j) {
    us4 w;
#pragma unroll
    for (int r = 0; r < 4; ++r) w[r] = f2bf(oaccT[j][r] * inv);
    *reinterpret_cast<us4*>(aout + 16 * j + 4 * lg) = w;
  }
}

// ---------------------------------------------------------------------------
extern "C" void kernel_launch(void* const* d_in, const int* in_sizes, int n_in,
                              void* d_out, int out_size, void* d_ws, size_t ws_size,
                              hipStream_t stream) {
  const float* q  = (const float*)d_in[0];
  const float* k  = (const float*)d_in[1];
  const float* v  = (const float*)d_in[2];
  const float* Wq = (const float*)d_in[3];
  const float* Wk = (const float*)d_in[4];
  const float* Wv = (const float*)d_in[5];
  const float* Wo = (const float*)d_in[6];
  float* out = (float*)d_out;

  char* ws = (char*)d_ws;
  const size_t MB = 1024 * 1024;
  us_t* WqT = (us_t*)(ws + 0 * MB);
  us_t* WkT = (us_t*)(ws + 2 * MB);
  us_t* WvT = (us_t*)(ws + 4 * MB);
  us_t* WoT = (us_t*)(ws + 6 * MB);
  us_t* Qh  = (us_t*)(ws + 8 * MB);
  us_t* Kh  = (us_t*)(ws + 16 * MB);
  us_t* Vt  = (us_t*)(ws + 24 * MB);
  us_t* AO  = (us_t*)(ws + 32 * MB);

  prep<<<dim3(32, 32, 4), 256, 0, stream>>>(Wq, Wk, Wv, Wo, WqT, WkT, WvT, WoT);

  proj3<<<768, 256, 0, stream>>>(q, k, v, WqT, WkT, WvT, Qh, Kh, Vt);

  attn64<<<dim3(32, 32), 256, 0, stream>>>(Qh, Kh, Vt, AO);

  gemmout<<<256, 256, 0, stream>>>(AO, WoT, out);
}

// Round 18
// 118.372 us; speedup vs baseline: 1.0084x; 1.0084x over previous
//
#include <hip/hip_runtime.h>
#include <type_traits>

#define S_LEN 2048
#define NHEAD 16
#define DHEAD 64
#define EMB   1024
#define NBATCH 2

typedef __bf16 bf16_t;
typedef bf16_t bf16x8 __attribute__((ext_vector_type(8)));
typedef float  f32x4  __attribute__((ext_vector_type(4)));
typedef unsigned short us_t;
typedef us_t   us8    __attribute__((ext_vector_type(8)));
typedef us_t   us4    __attribute__((ext_vector_type(4)));
typedef unsigned int u32x4 __attribute__((ext_vector_type(4)));
typedef unsigned int u32x2 __attribute__((ext_vector_type(2)));
typedef short  s16x4  __attribute__((ext_vector_type(4)));

static __device__ __forceinline__ bf16x8 ld_bf16x8(const us_t* p) {
  return __builtin_bit_cast(bf16x8, *reinterpret_cast<const us8*>(p));
}
static __device__ __forceinline__ us_t f2bf(float f) {
  bf16_t h = (bf16_t)f;
  return __builtin_bit_cast(us_t, h);
}
// packed f32x2 -> bf16x2 (1 instr; RNE on gfx950)
static __device__ __forceinline__ unsigned cvt_pk_bf16(float lo, float hi) {
  unsigned r;
  asm("v_cvt_pk_bf16_f32 %0, %1, %2" : "=v"(r) : "v"(lo), "v"(hi));
  return r;
}
#if __has_builtin(__builtin_amdgcn_exp2f)
#define EXP2(x) __builtin_amdgcn_exp2f(x)
#else
#define EXP2(x) exp2f(x)
#endif
// async global->LDS, 16B per lane. LDS dest = wave-uniform base + lane*16.
static __device__ __forceinline__ void gload16(const void* g, void* lds) {
  __builtin_amdgcn_global_load_lds((const __attribute__((address_space(1))) void*)g,
                                   (__attribute__((address_space(3))) void*)lds,
                                   16, 0, 0);
}

// ---------------- prep: weight transpose + fp32->bf16 (4 weights, z-dim) ----
__global__ __launch_bounds__(256) void prep(const float* __restrict__ W0,
                                            const float* __restrict__ W1,
                                            const float* __restrict__ W2,
                                            const float* __restrict__ W3,
                                            us_t* __restrict__ T0,
                                            us_t* __restrict__ T1,
                                            us_t* __restrict__ T2,
                                            us_t* __restrict__ T3) {
  __shared__ float tile[32][33];
  const int z = blockIdx.z;
  const float* W = (z == 0) ? W0 : (z == 1) ? W1 : (z == 2) ? W2 : W3;
  us_t* WT = (z == 0) ? T0 : (z == 1) ? T1 : (z == 2) ? T2 : T3;
  const int n0 = blockIdx.x * 32, k0 = blockIdx.y * 32;
  const int tx = threadIdx.x & 31, ty = threadIdx.x >> 5;
#pragma unroll
  for (int i = 0; i < 32; i += 8)
    tile[ty + i][tx] = W[(size_t)(k0 + ty + i) * EMB + n0 + tx];
  __syncthreads();
#pragma unroll
  for (int i = 0; i < 32; i += 8)
    WT[(size_t)(n0 + ty + i) * EMB + k0 + tx] = f2bf(tile[tx][ty + i]);
}

// ---------------- 128x128 GEMM core (BK=32) ---------------------------------
// AF32: fp32 A, depth-2 register pipeline, counted vmcnt + raw s_barrier.
// else: bf16 A via global_load_lds, 3-buffer deep staging.
//   MODE 0: bf16 [(b*16+h)][s][d]; MODE 1: bf16 [(b*16+h)][d][s] (us4 store);
//   MODE 2: fp32 [m][n]
template<int MODE, bool AF32>
static __device__ __forceinline__ void gemm_core(const void* __restrict__ Ap,
                                                 const us_t* __restrict__ BT,
                                                 void* __restrict__ O,
                                                 int mt, int nt,
                                                 char (*As)[8192], char (*Bs)[8192]) {
  const int lane = threadIdx.x & 63;
  const int wave = threadIdx.x >> 6;
  const int wm = (wave >> 1) * 64;
  const int wn = (wave & 1) * 64;
  const int lr = lane & 15;
  const int lg = lane >> 4;
  constexpr int NK = EMB / 32;   // 32

  f32x4 acc[4][4] = {};

  auto stageB = [&](int buf, int k0) {
#pragma unroll
    for (int i = 0; i < 2; ++i) {
      const int seg = wave * 2 + i;
      const int r = seg * 16 + (lane >> 2);
      gload16((const char*)BT + ((size_t)(nt * 128 + r) * EMB + k0) * 2 + (lane & 3) * 16,
              &Bs[buf][seg * 1024]);
    }
  };
  auto stageA16 = [&](int buf, int k0) {
#pragma unroll
    for (int i = 0; i < 2; ++i) {
      const int seg = wave * 2 + i;
      const int r = seg * 16 + (lane >> 2);
      gload16((const char*)Ap + ((size_t)(mt * 128 + r) * EMB + k0) * 2 + (lane & 3) * 16,
              &As[buf][seg * 1024]);
    }
  };
  auto a_load = [&](f32x4 (&ar)[2][2], int k0) {
#pragma unroll
    for (int i = 0; i < 2; ++i) {
      const int seg = wave * 2 + i;
      const int r = seg * 16 + (lane >> 2);
      const float* ap = (const float*)Ap + (size_t)(mt * 128 + r) * EMB + k0 + (lane & 3) * 8;
      ar[i][0] = *reinterpret_cast<const f32x4*>(ap);
      ar[i][1] = *reinterpret_cast<const f32x4*>(ap + 4);
    }
  };
  auto a_write = [&](f32x4 (&ar)[2][2], int buf) {
#pragma unroll
    for (int i = 0; i < 2; ++i) {
      const int seg = wave * 2 + i;
      u32x4 w = { cvt_pk_bf16(ar[i][0][0], ar[i][0][1]), cvt_pk_bf16(ar[i][0][2], ar[i][0][3]),
                  cvt_pk_bf16(ar[i][1][0], ar[i][1][1]), cvt_pk_bf16(ar[i][1][2], ar[i][1][3]) };
      *reinterpret_cast<u32x4*>(&As[buf][seg * 1024 + lane * 16]) = w;
    }
  };
  auto mfma_step = [&](int buf) {
    bf16x8 af[4], bfr[4];
#pragma unroll
    for (int i = 0; i < 4; ++i)
      af[i] = ld_bf16x8((const us_t*)&As[buf][(wm + 16 * i + lr) * 64 + lg * 16]);
#pragma unroll
    for (int j = 0; j < 4; ++j)
      bfr[j] = ld_bf16x8((const us_t*)&Bs[buf][(wn + 16 * j + lr) * 64 + lg * 16]);
#pragma unroll
    for (int i = 0; i < 4; ++i)
#pragma unroll
      for (int j = 0; j < 4; ++j)
        acc[i][j] = __builtin_amdgcn_mfma_f32_16x16x32_bf16(af[i], bfr[j], acc[i][j], 0, 0, 0);
  };

  if constexpr (AF32) {
    // vmcnt audit (per wave): a_load = 4 loads, stageB = 2 loads.
    // At each barrier: outstanding = B(next tile)=2 older + a_load(+2)=4
    // newer -> vmcnt(4) drains B only, keeps A flying one full iteration.
    f32x4 arE[2][2], arO[2][2];
    a_load(arE, 0);
    stageB(0, 0);
    a_write(arE, 0);                 // compiler auto-waits arE
    a_load(arO, 32);
    asm volatile("s_waitcnt vmcnt(4)" ::: "memory");
    asm volatile("s_waitcnt lgkmcnt(0)" ::: "memory");
    __builtin_amdgcn_s_barrier();

#pragma unroll 1
    for (int ks = 0; ks < NK - 4; ks += 2) {
      stageB(1, (ks + 1) * 32);
      mfma_step(0);
      a_write(arO, 1);
      a_load(arE, (ks + 2) * 32);
      asm volatile("s_waitcnt vmcnt(4)" ::: "memory");
      asm volatile("s_waitcnt lgkmcnt(0)" ::: "memory");
      __builtin_amdgcn_s_barrier();

      stageB(0, (ks + 2) * 32);
      mfma_step(1);
      a_write(arE, 0);
      a_load(arO, (ks + 3) * 32);
      asm volatile("s_waitcnt vmcnt(4)" ::: "memory");
      asm volatile("s_waitcnt lgkmcnt(0)" ::: "memory");
      __builtin_amdgcn_s_barrier();
    }
    // static tail: tiles 28,29,30,31
    stageB(1, 29 * 32);
    mfma_step(0);                    // tile 28
    a_write(arO, 1);                 // tile 29
    a_load(arE, 30 * 32);
    asm volatile("s_waitcnt vmcnt(4)" ::: "memory");
    asm volatile("s_waitcnt lgkmcnt(0)" ::: "memory");
    __builtin_amdgcn_s_barrier();

    stageB(0, 30 * 32);
    mfma_step(1);                    // tile 29
    a_write(arE, 0);                 // tile 30
    a_load(arO, 31 * 32);
    asm volatile("s_waitcnt vmcnt(4)" ::: "memory");
    asm volatile("s_waitcnt lgkmcnt(0)" ::: "memory");
    __builtin_amdgcn_s_barrier();

    stageB(1, 31 * 32);
    mfma_step(0);                    // tile 30
    a_write(arO, 1);                 // tile 31
    asm volatile("s_waitcnt vmcnt(0)" ::: "memory");
    asm volatile("s_waitcnt lgkmcnt(0)" ::: "memory");
    __builtin_amdgcn_s_barrier();

    mfma_step(1);                    // tile 31
  } else {
    // 3-buffer deep staging: stage ks+2 each iter; vmcnt(4) drains ks+1 only.
    stageA16(0, 0);  stageB(0, 0);
    stageA16(1, 32); stageB(1, 32);
    asm volatile("s_waitcnt vmcnt(4)" ::: "memory");
    __builtin_amdgcn_s_barrier();
    for (int ks = 0; ks < NK; ++ks) {
      const int cur = ks % 3;
      if (ks + 2 < NK) { stageA16((ks + 2) % 3, (ks + 2) * 32); stageB((ks + 2) % 3, (ks + 2) * 32); }
      mfma_step(cur);
      if (ks + 1 < NK) {
        if (ks + 2 < NK) asm volatile("s_waitcnt vmcnt(4)" ::: "memory");
        else             asm volatile("s_waitcnt vmcnt(0)" ::: "memory");
        __builtin_amdgcn_s_barrier();
      }
    }
  }

  const int crow = (lane >> 4) * 4;
#pragma unroll
  for (int i = 0; i < 4; ++i)
#pragma unroll
    for (int j = 0; j < 4; ++j) {
      if constexpr (MODE == 1) {
        // Vt: o[(bh*64+d)*2048 + s]; consecutive r == consecutive s -> us4
        const int m = mt * 128 + wm + 16 * i + crow;     // s base (aligned 4)
        const int n = nt * 128 + wn + 16 * j + lr;       // d
        const int b = m >> 11, s = m & (S_LEN - 1);
        const int h = n >> 6, d = n & 63;
        us4 w;
#pragma unroll
        for (int r = 0; r < 4; ++r) w[r] = f2bf(acc[i][j][r]);
        *reinterpret_cast<us4*>((us_t*)O +
            ((size_t)(b * NHEAD + h) * DHEAD + d) * S_LEN + s) = w;
      } else {
#pragma unroll
        for (int r = 0; r < 4; ++r) {
          const int m = mt * 128 + wm + 16 * i + crow + r;
          const int n = nt * 128 + wn + 16 * j + lr;
          const float val = acc[i][j][r];
          if constexpr (MODE == 2) {
            ((float*)O)[(size_t)m * EMB + n] = val;
          } else {
            us_t* o = (us_t*)O;
            const int b = m >> 11, s = m & (S_LEN - 1);
            const int h = n >> 6, d = n & 63;
            o[(((size_t)(b * NHEAD + h) * S_LEN + s) << 6) + d] = f2bf(val);
          }
        }
      }
    }
}

// merged projection GEMMs (fp32 A, fused cvt, counted-vmcnt pipeline)
__global__ __launch_bounds__(256, 3) void proj3(const float* __restrict__ A0,
                                                const float* __restrict__ A1,
                                                const float* __restrict__ A2,
                                                const us_t* __restrict__ B0,
                                                const us_t* __restrict__ B1,
                                                const us_t* __restrict__ B2,
                                                us_t* __restrict__ O0,
                                                us_t* __restrict__ O1,
                                                us_t* __restrict__ O2) {
  __shared__ char As[2][8192];
  __shared__ char Bs[2][8192];
  const int f = blockIdx.x;
  const int w = (f & 7) * 96 + (f >> 3);     // XCD x owns works [96x, 96x+96)
  const int z = w >> 8;                       // /256
  const int rem = w & 255;
  const int mt = rem >> 3, nt = rem & 7;      // nt fastest: 8 blocks share A panel
  const float* A = (z == 0) ? A0 : (z == 1) ? A1 : A2;
  const us_t* BT = (z == 0) ? B0 : (z == 1) ? B1 : B2;
  us_t* O = (z == 0) ? O0 : (z == 1) ? O1 : O2;
  if (z < 2)
    gemm_core<0, true>(A, BT, O, mt, nt, As, Bs);
  else
    gemm_core<1, true>(A, BT, O, mt, nt, As, Bs);
}

// final GEMM: AO[4096,1024] @ Wo -> fp32; flat grid 256, XCD-chunked
__global__ __launch_bounds__(256) void gemmout(const us_t* __restrict__ A,
                                               const us_t* __restrict__ BT,
                                               float* __restrict__ O) {
  __shared__ char As[3][8192];
  __shared__ char Bs[3][8192];
  const int f = blockIdx.x;
  const int w = (f & 7) * 32 + (f >> 3);
  const int mt = w >> 3, nt = w & 7;
  gemm_core<2, false>(A, BT, O, mt, nt, As, Bs);
}

// ---------------- flash attention, QBLK=64, swapped-QK^T (R8-verified) ------
// Qh,Kh: bf16 [B*H][S][64]; Vt: bf16 [B*H][64][S]; AO: bf16 [B][S][H*64]
// qt snake-remap: co-resident blocks {flat,+256,+512,+768} (same bh) get
// qt sums == 62 on every CU -> balanced load, no tail idling.
__global__ __launch_bounds__(256, 4) void attn64(const us_t* __restrict__ Qh,
                                                 const us_t* __restrict__ Kh,
                                                 const us_t* __restrict__ Vt,
                                                 us_t* __restrict__ AO) {
  __shared__ char Ks[2][8192];
  __shared__ char Vs[2][8192];
  const int flat = blockIdx.y * 32 + blockIdx.x;
  const int bh = (flat & 7) * 4 + ((flat >> 3) & 3);   // same bh -> same XCD
  const int g = flat >> 5;                             // 0..31
  const int Q = g >> 3, p = g & 7;
  const int qt = (Q == 0) ? 31 - p : (Q == 1) ? 16 + p : (Q == 2) ? 15 - p : p;
  const int lane = threadIdx.x & 63;
  const int wave = threadIdx.x >> 6;
  const int lr = lane & 15;
  const int lg = lane >> 4;
  const int q_glob = qt * 64 + wave * 16 + lr;         // this lane's q row

  const us_t* qbase = Qh + ((size_t)bh * S_LEN + q_glob) * DHEAD;
  bf16x8 qf[2] = { ld_bf16x8(qbase + lg * 8), ld_bf16x8(qbase + 32 + lg * 8) };

  const us_t* kbase0 = Kh + (size_t)bh * S_LEN * DHEAD;
  const us_t* vbase0 = Vt + (size_t)bh * DHEAD * S_LEN;

  // loop-invariant swizzled LDS byte offsets (SROA'd to VGPRs)
  int koff[8];
#pragma unroll
  for (int ks = 0; ks < 2; ++ks)
#pragma unroll
    for (int j = 0; j < 4; ++j)
      koff[ks * 4 + j] = (16 * j + lr) * 128 + ((ks * 64 + lg * 16) ^ ((lr & 7) << 4));
  int voff[16];
#pragma unroll
  for (int jk = 0; jk < 4; ++jk)
#pragma unroll
    for (int jd = 0; jd < 4; ++jd)
      voff[jk * 4 + jd] = (16 * jd + lr) * 128 + ((32 * jk + 8 * lg) ^ ((lr & 7) << 4));

  auto stage = [&](int buf, int t0) {
#pragma unroll
    for (int i = 0; i < 2; ++i) {
      const int seg = wave * 2 + i;
      const int r = seg * 8 + (lane >> 3);
      const int c16 = (lane & 7) ^ (lane >> 3);
      gload16(kbase0 + (size_t)(t0 + r) * DHEAD + c16 * 8, &Ks[buf][seg * 1024]);
      gload16(vbase0 + (size_t)r * S_LEN + t0 + c16 * 8, &Vs[buf][seg * 1024]);
    }
  };

  f32x4 oaccT[4] = {};          // O^T block jd: row d=16jd+4lg+reg, col q=lr
  float mrow = -1e9f;           // running max, log2-scaled domain
  float lsum = 0.f;             // per-lane partial sum
  const float c = 0.045084220f; // (1/32) * log2(e)

  stage(0, 0);
  __syncthreads();

  for (int tt = 0; tt <= qt; ++tt) {
    const int cur = tt & 1;
    if (tt < qt) stage(cur ^ 1, (tt + 1) * 64);

    // ---- S^T = K.Q^T : sc[j] rows t=16j+4lg+r, col q=lr ----
    f32x4 sc[4] = {};
    __builtin_amdgcn_s_setprio(1);
#pragma unroll
    for (int ks = 0; ks < 2; ++ks)
#pragma unroll
      for (int j = 0; j < 4; ++j) {
        bf16x8 ak = ld_bf16x8((const us_t*)&Ks[cur][koff[ks * 4 + j]]);
        sc[j] = __builtin_amdgcn_mfma_f32_16x16x32_bf16(ak, qf[ks], sc[j], 0, 0, 0);
      }
    __builtin_amdgcn_s_setprio(0);

    // ---- mask (diagonal tile only): keep t<q, plus [0,0] ----
    if (tt == qt) {
#pragma unroll
      for (int j = 0; j < 4; ++j)
#pragma unroll
        for (int r = 0; r < 4; ++r) {
          const int t_g = tt * 64 + 16 * j + 4 * lg + r;
          if (!((t_g < q_glob) || (q_glob == 0 && t_g == 0))) sc[j][r] = -1e30f;
        }
    }

    // ---- in-lane max (balanced tree); defer-max rescale (rarely taken) ----
    float mj[4];
#pragma unroll
    for (int j = 0; j < 4; ++j)
      mj[j] = fmaxf(fmaxf(sc[j][0], sc[j][1]), fmaxf(sc[j][2], sc[j][3]));
    const float mx = fmaxf(fmaxf(mj[0], mj[1]), fmaxf(mj[2], mj[3]));
    const float mxc = mx * c;
    if (__any(mxc > mrow + 8.f)) {
      float mc = mxc;
      mc = fmaxf(mc, __shfl_xor(mc, 16, 64));
      mc = fmaxf(mc, __shfl_xor(mc, 32, 64));
      const float m2 = fmaxf(mrow, mc);
      const float alpha = EXP2(mrow - m2);
      lsum *= alpha;
#pragma unroll
      for (int j = 0; j < 4; ++j)
#pragma unroll
        for (int r = 0; r < 4; ++r) oaccT[j][r] *= alpha;
      mrow = m2;
    }

    // ---- p = exp2(s*c - m); pack bf16 pairs via v_cvt_pk_bf16_f32 ----
    unsigned int pk[4][2];
    float ps = 0.f;
#pragma unroll
    for (int j = 0; j < 4; ++j) {
      float p0 = EXP2(__builtin_fmaf(sc[j][0], c, -mrow));
      float p1 = EXP2(__builtin_fmaf(sc[j][1], c, -mrow));
      float p2 = EXP2(__builtin_fmaf(sc[j][2], c, -mrow));
      float p3 = EXP2(__builtin_fmaf(sc[j][3], c, -mrow));
      ps += (p0 + p1) + (p2 + p3);
      pk[j][0] = cvt_pk_bf16(p0, p1);
      pk[j][1] = cvt_pk_bf16(p2, p3);
    }
    lsum += ps;

    // ---- O^T += V^T.P^T via 16x16x16: P C-layout IS the B-frag layout ----
    __builtin_amdgcn_s_setprio(1);
#pragma unroll
    for (int jk = 0; jk < 4; ++jk) {
      s16x4 pf = __builtin_bit_cast(s16x4, (u32x2){pk[jk][0], pk[jk][1]});
#pragma unroll
      for (int jd = 0; jd < 4; ++jd) {
        s16x4 av = __builtin_bit_cast(s16x4,
            *reinterpret_cast<const us4*>(&Vs[cur][voff[jk * 4 + jd]]));
        oaccT[jd] = __builtin_amdgcn_mfma_f32_16x16x16bf16_1k(av, pf, oaccT[jd], 0, 0, 0);
      }
    }
    __builtin_amdgcn_s_setprio(0);
    __syncthreads();
  }

  // ---- finalize: cross-lane lsum, normalize, store O^T ----
  lsum += __shfl_xor(lsum, 16, 64);
  lsum += __shfl_xor(lsum, 32, 64);
  const float inv = 1.0f / lsum;
  const int b = bh >> 4, h = bh & 15;
  us_t* aout = AO + (size_t)(b * S_LEN + q_glob) * EMB + h * DHEAD;
#pragma unroll
  for (int j = 0; j < 4; ++j) {
    us4 w;
#pragma unroll
    for (int r = 0; r < 4; ++r) w[r] = f2bf(oaccT[j][r] * inv);
    *reinterpret_cast<us4*>(aout + 16 * j + 4 * lg) = w;
  }
}

// ---------------------------------------------------------------------------
extern "C" void kernel_launch(void* const* d_in, const int* in_sizes, int n_in,
                              void* d_out, int out_size, void* d_ws, size_t ws_size,
                              hipStream_t stream) {
  const float* q  = (const float*)d_in[0];
  const float* k  = (const float*)d_in[1];
  const float* v  = (const float*)d_in[2];
  const float* Wq = (const float*)d_in[3];
  const float* Wk = (const float*)d_in[4];
  const float* Wv = (const float*)d_in[5];
  const float* Wo = (const float*)d_in[6];
  float* out = (float*)d_out;

  char* ws = (char*)d_ws;
  const size_t MB = 1024 * 1024;
  us_t* WqT = (us_t*)(ws + 0 * MB);
  us_t* WkT = (us_t*)(ws + 2 * MB);
  us_t* WvT = (us_t*)(ws + 4 * MB);
  us_t* WoT = (us_t*)(ws + 6 * MB);
  us_t* Qh  = (us_t*)(ws + 8 * MB);
  us_t* Kh  = (us_t*)(ws + 16 * MB);
  us_t* Vt  = (us_t*)(ws + 24 * MB);
  us_t* AO  = (us_t*)(ws + 32 * MB);

  prep<<<dim3(32, 32, 4), 256, 0, stream>>>(Wq, Wk, Wv, Wo, WqT, WkT, WvT, WoT);

  proj3<<<768, 256, 0, stream>>>(q, k, v, WqT, WkT, WvT, Qh, Kh, Vt);

  attn64<<<dim3(32, 32), 256, 0, stream>>>(Qh, Kh, Vt, AO);

  gemmout<<<256, 256, 0, stream>>>(AO, WoT, out);
}